// Round 9
// baseline (342.936 us; speedup 1.0000x reference)
//
#include <hip/hip_runtime.h>
#include <math.h>

#define N_NODES 50000
#define E_ORIG  500000
#define E_TOT   550000
#define NB      196   // scan blocks: 196*256 = 50176 >= N_NODES

typedef _Float16 half8 __attribute__((ext_vector_type(8)));
typedef _Float16 half4 __attribute__((ext_vector_type(4)));
typedef float    v4f   __attribute__((ext_vector_type(4)));

// ------------------------------------------------------------------
// CSR build (group edges by destination node)
// ------------------------------------------------------------------
__global__ void k_count(const int* __restrict__ ei, int* __restrict__ deg) {
    int e = blockIdx.x * blockDim.x + threadIdx.x;
    if (e >= E_TOT) return;
    int d = (e < E_ORIG) ? ei[E_ORIG + e] : (e - E_ORIG);
    atomicAdd(&deg[d], 1);
}

__global__ __launch_bounds__(256) void k_blocksum(const int* __restrict__ deg,
                                                  int* __restrict__ bsum) {
    int t = threadIdx.x;
    int i = blockIdx.x * 256 + t;
    int v = (i < N_NODES) ? deg[i] : 0;
#pragma unroll
    for (int mk = 1; mk < 64; mk <<= 1) v += __shfl_xor(v, mk, 64);
    __shared__ int ws[4];
    if ((t & 63) == 0) ws[t >> 6] = v;
    __syncthreads();
    if (t == 0) bsum[blockIdx.x] = ws[0] + ws[1] + ws[2] + ws[3];
}

__global__ __launch_bounds__(256) void k_scanbsum(const int* __restrict__ bsum,
                                                  int* __restrict__ boff) {
    __shared__ int s[256];
    int t = threadIdx.x;
    int v = (t < NB) ? bsum[t] : 0;
    s[t] = v;
    __syncthreads();
    for (int o = 1; o < 256; o <<= 1) {
        int x = (t >= o) ? s[t - o] : 0;
        __syncthreads();
        s[t] += x;
        __syncthreads();
    }
    if (t <= NB) boff[t] = (t == 0) ? 0 : s[t - 1];
}

__global__ __launch_bounds__(256) void k_offsets(const int* __restrict__ deg,
                                                 const int* __restrict__ boff,
                                                 int* __restrict__ offsets,
                                                 int* __restrict__ cur) {
    __shared__ int s[256];
    int t = threadIdx.x;
    int i = blockIdx.x * 256 + t;
    int v = (i < N_NODES) ? deg[i] : 0;
    s[t] = v;
    __syncthreads();
    for (int o = 1; o < 256; o <<= 1) {
        int x = (t >= o) ? s[t - o] : 0;
        __syncthreads();
        s[t] += x;
        __syncthreads();
    }
    int off = boff[blockIdx.x] + s[t] - v;  // exclusive
    if (i <= N_NODES) {
        offsets[i] = off;
        if (i < N_NODES) cur[i] = off;
    }
}

__global__ void k_scatter(const int* __restrict__ ei, int* __restrict__ cur,
                          int* __restrict__ csr_src, int* __restrict__ csr_dst) {
    int e = blockIdx.x * blockDim.x + threadIdx.x;
    if (e >= E_TOT) return;
    int s, d;
    if (e < E_ORIG) { s = ei[e]; d = ei[E_ORIG + e]; }
    else            { s = e - E_ORIG; d = s; }
    int slot = atomicAdd(&cur[d], 1);
    csr_src[slot] = s;
    csr_dst[slot] = d;
}

// ------------------------------------------------------------------
// Fused prep: zero deg, W1/W2 transpose+cast, vs2/vd2 = W2 @ a2
// ------------------------------------------------------------------
__global__ void k_prepw(const float* __restrict__ W1, const float* __restrict__ W2,
                        const float* __restrict__ as2, const float* __restrict__ ad2,
                        _Float16* __restrict__ w1t, _Float16* __restrict__ w2t,
                        float* __restrict__ vs2, float* __restrict__ vd2,
                        int* __restrict__ deg) {
    int i = blockIdx.x * blockDim.x + threadIdx.x;
    if (i < 128 * 256) {
        int k = i >> 8, c = i & 255;
        w1t[(size_t)c * 128 + k] = (_Float16)W1[i];
        return;
    }
    int j = i - 128 * 256;
    if (j < 256 * 256) {
        int k = j >> 8, c = j & 255;
        w2t[(size_t)c * 256 + k] = (_Float16)W2[j];
        return;
    }
    j -= 256 * 256;
    if (j < 256) {
        float s = 0.f, d = 0.f;
        for (int c = 0; c < 256; c++) {
            float w = W2[(size_t)j * 256 + c];
            s += w * as2[c];
            d += w * ad2[c];
        }
        vs2[j] = s;
        vd2[j] = d;
        return;
    }
    j -= 256;
    if (j < N_NODES) deg[j] = 0;
}

// ------------------------------------------------------------------
// Edge-weight precompute (validated R8)
// ------------------------------------------------------------------
__global__ __launch_bounds__(256) void k_wts1(
    const int* __restrict__ csr_src, const int* __restrict__ csr_dst,
    const float* __restrict__ es, const float* __restrict__ ed,
    float* __restrict__ w1w) {
    int i = blockIdx.x * blockDim.x + threadIdx.x;
    if (i >= E_TOT * 8) return;
    int e = i >> 3, h = i & 7;
    int s = csr_src[e], d = csr_dst[e];
    float l = es[(size_t)s * 8 + h] + ed[(size_t)d * 8 + h];
    l = l > 0.f ? l : 0.2f * l;
    w1w[i] = __expf(l);
}

__global__ __launch_bounds__(256) void k_wts2(
    const int* __restrict__ csr_src, const int* __restrict__ csr_dst,
    const float* __restrict__ es2, const float* __restrict__ ed2,
    float* __restrict__ w2w) {
    int e = blockIdx.x * blockDim.x + threadIdx.x;
    if (e >= E_TOT) return;
    float l = es2[csr_src[e]] + ed2[csr_dst[e]];
    l = l > 0.f ? l : 0.2f * l;
    w2w[e] = __expf(l);
}

// ------------------------------------------------------------------
// GEMM1: H[N,256] = cvt16(X[N,128]) @ w1t^T + fused es/ed.
// 32-row tile; 2-pass LDS epilogue (8.4 KB) for occupancy.
// ------------------------------------------------------------------
__global__ __launch_bounds__(256) void k_gemm1(
    const float* __restrict__ X, const _Float16* __restrict__ Bt,
    const float* __restrict__ a_s, const float* __restrict__ a_d,
    _Float16* __restrict__ H, float* __restrict__ es, float* __restrict__ ed) {
    int t = threadIdx.x, w = t >> 6, lane = t & 63;
    int quad = lane >> 4, l16 = lane & 15;
    int row0 = blockIdx.x * 32;
    int colbase = w * 64;

    v4f acc[2][4];
#pragma unroll
    for (int i = 0; i < 2; i++)
#pragma unroll
        for (int j = 0; j < 4; j++) acc[i][j] = (v4f){0.f, 0.f, 0.f, 0.f};

    int r0 = row0 + l16;      if (r0 >= N_NODES) r0 = N_NODES - 1;
    int r1 = row0 + 16 + l16; if (r1 >= N_NODES) r1 = N_NODES - 1;
    const float4* a0p = (const float4*)(X + (size_t)r0 * 128) + quad * 2;
    const float4* a1p = (const float4*)(X + (size_t)r1 * 128) + quad * 2;
    const half8* bp[4];
#pragma unroll
    for (int ct = 0; ct < 4; ct++)
        bp[ct] = (const half8*)(Bt + (size_t)(colbase + ct * 16 + l16) * 128 + quad * 8);

#pragma unroll
    for (int kc = 0; kc < 4; kc++) {
        float4 f0 = a0p[kc * 8], f1 = a0p[kc * 8 + 1];
        float4 f2 = a1p[kc * 8], f3 = a1p[kc * 8 + 1];
        half8 av0 = (half8){(_Float16)f0.x, (_Float16)f0.y, (_Float16)f0.z, (_Float16)f0.w,
                            (_Float16)f1.x, (_Float16)f1.y, (_Float16)f1.z, (_Float16)f1.w};
        half8 av1 = (half8){(_Float16)f2.x, (_Float16)f2.y, (_Float16)f2.z, (_Float16)f2.w,
                            (_Float16)f3.x, (_Float16)f3.y, (_Float16)f3.z, (_Float16)f3.w};
#pragma unroll
        for (int ct = 0; ct < 4; ct++) {
            half8 bv = bp[ct][kc * 4];
            acc[0][ct] = __builtin_amdgcn_mfma_f32_16x16x32_f16(av0, bv, acc[0][ct], 0, 0, 0);
            acc[1][ct] = __builtin_amdgcn_mfma_f32_16x16x32_f16(av1, bv, acc[1][ct], 0, 0, 0);
        }
    }

    float asv[4], adv[4];
#pragma unroll
    for (int ct = 0; ct < 4; ct++) {
        asv[ct] = a_s[colbase + ct * 16 + l16];
        adv[ct] = a_d[colbase + ct * 16 + l16];
    }
#pragma unroll
    for (int rt = 0; rt < 2; rt++) {
#pragma unroll
        for (int hp = 0; hp < 2; hp++) {
#pragma unroll
            for (int reg = 0; reg < 4; reg++) {
                float ps = acc[rt][2 * hp][reg] * asv[2 * hp] +
                           acc[rt][2 * hp + 1][reg] * asv[2 * hp + 1];
                float pd = acc[rt][2 * hp][reg] * adv[2 * hp] +
                           acc[rt][2 * hp + 1][reg] * adv[2 * hp + 1];
#pragma unroll
                for (int mk = 1; mk < 16; mk <<= 1) {
                    ps += __shfl_xor(ps, mk, 64);
                    pd += __shfl_xor(pd, mk, 64);
                }
                if (l16 == 0) {
                    int row = row0 + rt * 16 + quad * 4 + reg;
                    if (row < N_NODES) {
                        int head = w * 2 + hp;
                        es[(size_t)row * 8 + head] = ps;
                        ed[(size_t)row * 8 + head] = pd;
                    }
                }
            }
        }
    }

    // 2-pass LDS-staged f16 store (16 rows per pass, 8.4 KB)
    __shared__ _Float16 SH[16][264];
#pragma unroll
    for (int rt = 0; rt < 2; rt++) {
        if (rt) __syncthreads();
#pragma unroll
        for (int ct = 0; ct < 4; ct++)
#pragma unroll
            for (int reg = 0; reg < 4; reg++)
                SH[quad * 4 + reg][colbase + ct * 16 + l16] = (_Float16)acc[rt][ct][reg];
        __syncthreads();
#pragma unroll
        for (int j = 0; j < 2; j++) {
            int c = j * 256 + t;
            int row = c >> 5, col8 = c & 31;
            int gr = row0 + rt * 16 + row;
            if (gr < N_NODES)
                *(half8*)(H + (size_t)gr * 256 + col8 * 8) = *(const half8*)&SH[row][col8 * 8];
        }
    }
}

// ------------------------------------------------------------------
// GEMM2: OUT[N,256] = A[N,256] @ w2t^T + bias, f32 out.
// 32-row tile; 2-pass LDS epilogue (16.6 KB) for occupancy.
// ------------------------------------------------------------------
__global__ __launch_bounds__(256) void k_gemm2(
    const _Float16* __restrict__ A, const _Float16* __restrict__ Bt,
    const float* __restrict__ bias, float* __restrict__ OUT) {
    int t = threadIdx.x, w = t >> 6, lane = t & 63;
    int quad = lane >> 4, l16 = lane & 15;
    int row0 = blockIdx.x * 32;
    int colbase = w * 64;

    v4f acc[2][4];
#pragma unroll
    for (int i = 0; i < 2; i++)
#pragma unroll
        for (int j = 0; j < 4; j++) acc[i][j] = (v4f){0.f, 0.f, 0.f, 0.f};

    int r0 = row0 + l16;      if (r0 >= N_NODES) r0 = N_NODES - 1;
    int r1 = row0 + 16 + l16; if (r1 >= N_NODES) r1 = N_NODES - 1;
    const half8* a0 = (const half8*)(A + (size_t)r0 * 256 + quad * 8);
    const half8* a1 = (const half8*)(A + (size_t)r1 * 256 + quad * 8);
    const half8* bp[4];
#pragma unroll
    for (int ct = 0; ct < 4; ct++)
        bp[ct] = (const half8*)(Bt + (size_t)(colbase + ct * 16 + l16) * 256 + quad * 8);

#pragma unroll
    for (int kc = 0; kc < 8; kc++) {
        half8 av0 = a0[kc * 4];
        half8 av1 = a1[kc * 4];
#pragma unroll
        for (int ct = 0; ct < 4; ct++) {
            half8 bv = bp[ct][kc * 4];
            acc[0][ct] = __builtin_amdgcn_mfma_f32_16x16x32_f16(av0, bv, acc[0][ct], 0, 0, 0);
            acc[1][ct] = __builtin_amdgcn_mfma_f32_16x16x32_f16(av1, bv, acc[1][ct], 0, 0, 0);
        }
    }

    __shared__ float SF[16][260];
#pragma unroll
    for (int rt = 0; rt < 2; rt++) {
        if (rt) __syncthreads();
#pragma unroll
        for (int ct = 0; ct < 4; ct++)
#pragma unroll
            for (int reg = 0; reg < 4; reg++)
                SF[quad * 4 + reg][colbase + ct * 16 + l16] = acc[rt][ct][reg];
        __syncthreads();
#pragma unroll
        for (int j = 0; j < 4; j++) {
            int c = j * 256 + t;
            int row = c >> 6, c4 = c & 63;
            int gr = row0 + rt * 16 + row;
            if (gr < N_NODES) {
                float4 v = *(const float4*)&SF[row][c4 * 4];
                float4 bb = ((const float4*)bias)[c4];
                float4 o = make_float4(v.x + bb.x, v.y + bb.y, v.z + bb.z, v.w + bb.w);
                *(float4*)(OUT + (size_t)gr * 256 + c4 * 4) = o;
            }
        }
    }
}

// ------------------------------------------------------------------
// Layer-1 aggregation: wave-per-node, two 32-lane halves process
// even/odd edges concurrently; lane covers 8 channels (half8, 16 B).
// Cross-half combine = shfl_xor(32). Barrier-free. Fused es2/ed2.
// ------------------------------------------------------------------
__global__ __launch_bounds__(256) void k_agg1(
    const _Float16* __restrict__ H1, const float* __restrict__ w1w,
    const int* __restrict__ offsets, const int* __restrict__ csr_src,
    const float* __restrict__ b1, const float* __restrict__ vs2,
    const float* __restrict__ vd2, _Float16* __restrict__ out1,
    float* __restrict__ es2, float* __restrict__ ed2) {
    int t = threadIdx.x, w = t >> 6, lane = t & 63;
    int n = blockIdx.x * 4 + w;   // 12500 x 4 waves = 50000
    int half = lane >> 5;         // 0: even edges, 1: odd edges
    int c8 = lane & 31;           // channel octet: channels c8*8..+8
    int hB = c8 >> 2;             // head of this octet
    int beg = offsets[n];
    int deg = offsets[n + 1] - beg;

    const char* __restrict__ Hb = (const char*)H1 + c8 * 16;
    const float* __restrict__ pw = w1w + (size_t)beg * 8 + hB;
    float a0 = 0.f, a1 = 0.f, a2 = 0.f, a3 = 0.f;
    float a4 = 0.f, a5 = 0.f, a6 = 0.f, a7 = 0.f, den = 0.f;

    for (int base = 0; base < deg; base += 64) {
        int rem = deg - base; if (rem > 64) rem = 64;
        int idx = beg + base + lane;
        if (idx >= E_TOT) idx = E_TOT - 1;
        int sreg = csr_src[idx];
        for (int i = half; i < rem; i += 2) {
            int s0 = __shfl(sreg, i);
            float w0 = pw[(base + i) * 8];
            half8 h = *(const half8*)(Hb + ((size_t)(unsigned)s0 << 9));
            a0 += w0 * (float)h[0]; a1 += w0 * (float)h[1];
            a2 += w0 * (float)h[2]; a3 += w0 * (float)h[3];
            a4 += w0 * (float)h[4]; a5 += w0 * (float)h[5];
            a6 += w0 * (float)h[6]; a7 += w0 * (float)h[7];
            den += w0;
        }
    }

    // combine even/odd halves
    a0 += __shfl_xor(a0, 32, 64); a1 += __shfl_xor(a1, 32, 64);
    a2 += __shfl_xor(a2, 32, 64); a3 += __shfl_xor(a3, 32, 64);
    a4 += __shfl_xor(a4, 32, 64); a5 += __shfl_xor(a5, 32, 64);
    a6 += __shfl_xor(a6, 32, 64); a7 += __shfl_xor(a7, 32, 64);
    den += __shfl_xor(den, 32, 64);

    float r = 1.f / (den + 1e-16f);
    float4 bl = ((const float4*)b1)[c8 * 2];
    float4 bh = ((const float4*)b1)[c8 * 2 + 1];
    float o0 = a0 * r + bl.x, o1 = a1 * r + bl.y;
    float o2 = a2 * r + bl.z, o3 = a3 * r + bl.w;
    float o4 = a4 * r + bh.x, o5 = a5 * r + bh.y;
    float o6 = a6 * r + bh.z, o7 = a7 * r + bh.w;
    o0 = o0 > 0.f ? o0 : __expf(o0) - 1.f;
    o1 = o1 > 0.f ? o1 : __expf(o1) - 1.f;
    o2 = o2 > 0.f ? o2 : __expf(o2) - 1.f;
    o3 = o3 > 0.f ? o3 : __expf(o3) - 1.f;
    o4 = o4 > 0.f ? o4 : __expf(o4) - 1.f;
    o5 = o5 > 0.f ? o5 : __expf(o5) - 1.f;
    o6 = o6 > 0.f ? o6 : __expf(o6) - 1.f;
    o7 = o7 > 0.f ? o7 : __expf(o7) - 1.f;
    if (half == 0) {
        half8 hv = (half8){(_Float16)o0, (_Float16)o1, (_Float16)o2, (_Float16)o3,
                           (_Float16)o4, (_Float16)o5, (_Float16)o6, (_Float16)o7};
        *((half8*)(out1 + (size_t)n * 256) + c8) = hv;
    }

    // fused layer-2 attention coefficients (lanes 0-31 hold all octets)
    float4 vsl = ((const float4*)vs2)[c8 * 2];
    float4 vsh = ((const float4*)vs2)[c8 * 2 + 1];
    float4 vdl = ((const float4*)vd2)[c8 * 2];
    float4 vdh = ((const float4*)vd2)[c8 * 2 + 1];
    float ps = o0 * vsl.x + o1 * vsl.y + o2 * vsl.z + o3 * vsl.w +
               o4 * vsh.x + o5 * vsh.y + o6 * vsh.z + o7 * vsh.w;
    float pd = o0 * vdl.x + o1 * vdl.y + o2 * vdl.z + o3 * vdl.w +
               o4 * vdh.x + o5 * vdh.y + o6 * vdh.z + o7 * vdh.w;
#pragma unroll
    for (int mk = 1; mk < 32; mk <<= 1) {
        ps += __shfl_xor(ps, mk, 64);
        pd += __shfl_xor(pd, mk, 64);
    }
    if (lane == 0) { es2[n] = ps; ed2[n] = pd; }
}

// ------------------------------------------------------------------
// Layer-2 aggregation: same structure, single-head weights ride in
// the coalesced window (shfl broadcast).
// ------------------------------------------------------------------
__global__ __launch_bounds__(256) void k_agg2(
    const _Float16* __restrict__ O1, const float* __restrict__ w2w,
    const int* __restrict__ offsets, const int* __restrict__ csr_src,
    _Float16* __restrict__ xagg) {
    int t = threadIdx.x, w = t >> 6, lane = t & 63;
    int n = blockIdx.x * 4 + w;
    int half = lane >> 5, c8 = lane & 31;
    int beg = offsets[n];
    int deg = offsets[n + 1] - beg;

    const char* __restrict__ Ob = (const char*)O1 + c8 * 16;
    float a0 = 0.f, a1 = 0.f, a2 = 0.f, a3 = 0.f;
    float a4 = 0.f, a5 = 0.f, a6 = 0.f, a7 = 0.f, den = 0.f;

    for (int base = 0; base < deg; base += 64) {
        int rem = deg - base; if (rem > 64) rem = 64;
        int idx = beg + base + lane;
        if (idx >= E_TOT) idx = E_TOT - 1;
        int sreg = csr_src[idx];
        float wreg = w2w[idx];
        for (int i = half; i < rem; i += 2) {
            int s0 = __shfl(sreg, i);
            float w0 = __shfl(wreg, i);
            half8 h = *(const half8*)(Ob + ((size_t)(unsigned)s0 << 9));
            a0 += w0 * (float)h[0]; a1 += w0 * (float)h[1];
            a2 += w0 * (float)h[2]; a3 += w0 * (float)h[3];
            a4 += w0 * (float)h[4]; a5 += w0 * (float)h[5];
            a6 += w0 * (float)h[6]; a7 += w0 * (float)h[7];
            den += w0;
        }
    }

    a0 += __shfl_xor(a0, 32, 64); a1 += __shfl_xor(a1, 32, 64);
    a2 += __shfl_xor(a2, 32, 64); a3 += __shfl_xor(a3, 32, 64);
    a4 += __shfl_xor(a4, 32, 64); a5 += __shfl_xor(a5, 32, 64);
    a6 += __shfl_xor(a6, 32, 64); a7 += __shfl_xor(a7, 32, 64);
    den += __shfl_xor(den, 32, 64);

    float r = 1.f / (den + 1e-16f);
    if (half == 0) {
        half8 hv = (half8){(_Float16)(a0 * r), (_Float16)(a1 * r),
                           (_Float16)(a2 * r), (_Float16)(a3 * r),
                           (_Float16)(a4 * r), (_Float16)(a5 * r),
                           (_Float16)(a6 * r), (_Float16)(a7 * r)};
        *((half8*)(xagg + (size_t)n * 256) + c8) = hv;
    }
}

// ------------------------------------------------------------------
extern "C" void kernel_launch(void* const* d_in, const int* in_sizes, int n_in,
                              void* d_out, int out_size, void* d_ws, size_t ws_size,
                              hipStream_t stream) {
    const float* x   = (const float*)d_in[0];
    const int*   ei  = (const int*)d_in[1];
    const float* W1  = (const float*)d_in[2];
    const float* as1 = (const float*)d_in[3];
    const float* ad1 = (const float*)d_in[4];
    const float* b1  = (const float*)d_in[5];
    const float* W2  = (const float*)d_in[6];
    const float* as2 = (const float*)d_in[7];
    const float* ad2 = (const float*)d_in[8];
    const float* b2  = (const float*)d_in[9];
    float* out = (float*)d_out;

    char* ws = (char*)d_ws;
    size_t off = 0;
    auto alloc = [&](size_t bytes) {
        void* p = ws + off;
        off = (off + bytes + 255) & ~(size_t)255;
        return p;
    };
    _Float16* h1h     = (_Float16*)alloc((size_t)N_NODES * 256 * 2);
    _Float16* out1h   = (_Float16*)alloc((size_t)N_NODES * 256 * 2);
    _Float16* xagg    = (_Float16*)alloc((size_t)N_NODES * 256 * 2);
    _Float16* w1t     = (_Float16*)alloc((size_t)128 * 256 * 2);
    _Float16* w2t     = (_Float16*)alloc((size_t)256 * 256 * 2);
    float*    es1     = (float*)alloc((size_t)N_NODES * 8 * 4);
    float*    ed1     = (float*)alloc((size_t)N_NODES * 8 * 4);
    float*    es2     = (float*)alloc((size_t)N_NODES * 4);
    float*    ed2     = (float*)alloc((size_t)N_NODES * 4);
    float*    vs2     = (float*)alloc(256 * 4);
    float*    vd2     = (float*)alloc(256 * 4);
    float*    w1w     = (float*)alloc((size_t)E_TOT * 8 * 4);
    float*    w2w     = (float*)alloc((size_t)E_TOT * 4);
    int*      deg     = (int*)alloc((size_t)N_NODES * 4);
    int*      offsets = (int*)alloc((size_t)(N_NODES + 1) * 4);
    int*      cur     = (int*)alloc((size_t)N_NODES * 4);
    int*      csr_src = (int*)alloc((size_t)E_TOT * 4);
    int*      csr_dst = (int*)alloc((size_t)E_TOT * 4);
    int*      bsum    = (int*)alloc((size_t)NB * 4);
    int*      boff    = (int*)alloc((size_t)(NB + 1) * 4);

    const int TB = 256;
    int gridE = (E_TOT + TB - 1) / TB;
    int gridG = (N_NODES + 31) / 32;   // 32-row GEMM tiles
    int gridA = N_NODES / 4;           // wave-per-node

    // prep (includes deg zeroing) then CSR build
    int prepN = 128 * 256 + 256 * 256 + 256 + N_NODES;
    k_prepw<<<(prepN + TB - 1) / TB, TB, 0, stream>>>(W1, W2, as2, ad2,
                                                      w1t, w2t, vs2, vd2, deg);
    k_count<<<gridE, TB, 0, stream>>>(ei, deg);
    k_blocksum<<<NB, TB, 0, stream>>>(deg, bsum);
    k_scanbsum<<<1, TB, 0, stream>>>(bsum, boff);
    k_offsets<<<NB, TB, 0, stream>>>(deg, boff, offsets, cur);
    k_scatter<<<gridE, TB, 0, stream>>>(ei, cur, csr_src, csr_dst);

    // layer 1
    k_gemm1<<<gridG, TB, 0, stream>>>(x, w1t, as1, ad1, h1h, es1, ed1);
    k_wts1<<<(E_TOT * 8 + TB - 1) / TB, TB, 0, stream>>>(csr_src, csr_dst,
                                                         es1, ed1, w1w);
    k_agg1<<<gridA, TB, 0, stream>>>(h1h, w1w, offsets, csr_src, b1,
                                     vs2, vd2, out1h, es2, ed2);

    // layer 2: weights, aggregate (linearity), GEMM straight to d_out
    k_wts2<<<gridE, TB, 0, stream>>>(csr_src, csr_dst, es2, ed2, w2w);
    k_agg2<<<gridA, TB, 0, stream>>>(out1h, w2w, offsets, csr_src, xagg);
    k_gemm2<<<gridG, TB, 0, stream>>>(xagg, w2t, b2, out);
}

// Round 10
// 320.023 us; speedup vs baseline: 1.0716x; 1.0716x over previous
//
#include <hip/hip_runtime.h>
#include <math.h>

#define N_NODES 50000
#define E_ORIG  500000
#define E_TOT   550000
#define NB      196   // scan blocks: 196*256 = 50176 >= N_NODES

typedef _Float16 half8 __attribute__((ext_vector_type(8)));
typedef _Float16 half4 __attribute__((ext_vector_type(4)));
typedef float    v4f   __attribute__((ext_vector_type(4)));

// ------------------------------------------------------------------
// Fused prep: W1/W2 transpose+cast, vs2/vd2 = W2 @ a2, edge degree
// count (deg pre-zeroed by hipMemsetAsync).
// ------------------------------------------------------------------
__global__ void k_prepw(const float* __restrict__ W1, const float* __restrict__ W2,
                        const float* __restrict__ as2, const float* __restrict__ ad2,
                        const int* __restrict__ ei,
                        _Float16* __restrict__ w1t, _Float16* __restrict__ w2t,
                        float* __restrict__ vs2, float* __restrict__ vd2,
                        int* __restrict__ deg) {
    int i = blockIdx.x * blockDim.x + threadIdx.x;
    if (i < E_TOT) {
        int d = (i < E_ORIG) ? ei[E_ORIG + i] : (i - E_ORIG);
        atomicAdd(&deg[d], 1);
        return;
    }
    int j = i - E_TOT;
    if (j < 128 * 256) {
        int k = j >> 8, c = j & 255;
        w1t[(size_t)c * 128 + k] = (_Float16)W1[j];
        return;
    }
    j -= 128 * 256;
    if (j < 256 * 256) {
        int k = j >> 8, c = j & 255;
        w2t[(size_t)c * 256 + k] = (_Float16)W2[j];
        return;
    }
    j -= 256 * 256;
    if (j < 256) {
        float s = 0.f, d = 0.f;
        for (int c = 0; c < 256; c++) {
            float w = W2[(size_t)j * 256 + c];
            s += w * as2[c];
            d += w * ad2[c];
        }
        vs2[j] = s;
        vd2[j] = d;
    }
}

// ------------------------------------------------------------------
// CSR scan + scatter
// ------------------------------------------------------------------
__global__ __launch_bounds__(256) void k_blocksum(const int* __restrict__ deg,
                                                  int* __restrict__ bsum) {
    int t = threadIdx.x;
    int i = blockIdx.x * 256 + t;
    int v = (i < N_NODES) ? deg[i] : 0;
#pragma unroll
    for (int mk = 1; mk < 64; mk <<= 1) v += __shfl_xor(v, mk, 64);
    __shared__ int ws[4];
    if ((t & 63) == 0) ws[t >> 6] = v;
    __syncthreads();
    if (t == 0) bsum[blockIdx.x] = ws[0] + ws[1] + ws[2] + ws[3];
}

__global__ __launch_bounds__(256) void k_scanbsum(const int* __restrict__ bsum,
                                                  int* __restrict__ boff) {
    __shared__ int s[256];
    int t = threadIdx.x;
    int v = (t < NB) ? bsum[t] : 0;
    s[t] = v;
    __syncthreads();
    for (int o = 1; o < 256; o <<= 1) {
        int x = (t >= o) ? s[t - o] : 0;
        __syncthreads();
        s[t] += x;
        __syncthreads();
    }
    if (t <= NB) boff[t] = (t == 0) ? 0 : s[t - 1];
}

__global__ __launch_bounds__(256) void k_offsets(const int* __restrict__ deg,
                                                 const int* __restrict__ boff,
                                                 int* __restrict__ offsets,
                                                 int* __restrict__ cur) {
    __shared__ int s[256];
    int t = threadIdx.x;
    int i = blockIdx.x * 256 + t;
    int v = (i < N_NODES) ? deg[i] : 0;
    s[t] = v;
    __syncthreads();
    for (int o = 1; o < 256; o <<= 1) {
        int x = (t >= o) ? s[t - o] : 0;
        __syncthreads();
        s[t] += x;
        __syncthreads();
    }
    int off = boff[blockIdx.x] + s[t] - v;  // exclusive
    if (i <= N_NODES) {
        offsets[i] = off;
        if (i < N_NODES) cur[i] = off;
    }
}

__global__ void k_scatter(const int* __restrict__ ei, int* __restrict__ cur,
                          int* __restrict__ csr_src) {
    int e = blockIdx.x * blockDim.x + threadIdx.x;
    if (e >= E_TOT) return;
    int s, d;
    if (e < E_ORIG) { s = ei[e]; d = ei[E_ORIG + e]; }
    else            { s = e - E_ORIG; d = s; }
    int slot = atomicAdd(&cur[d], 1);
    csr_src[slot] = s;
}

// ------------------------------------------------------------------
// GEMM1: H[N,256] = cvt16(X[N,128]) @ w1t^T + fused es/ed.
// 32-row tile; 2-pass LDS epilogue (8.4 KB).
// ------------------------------------------------------------------
__global__ __launch_bounds__(256) void k_gemm1(
    const float* __restrict__ X, const _Float16* __restrict__ Bt,
    const float* __restrict__ a_s, const float* __restrict__ a_d,
    _Float16* __restrict__ H, float* __restrict__ es, float* __restrict__ ed) {
    int t = threadIdx.x, w = t >> 6, lane = t & 63;
    int quad = lane >> 4, l16 = lane & 15;
    int row0 = blockIdx.x * 32;
    int colbase = w * 64;

    v4f acc[2][4];
#pragma unroll
    for (int i = 0; i < 2; i++)
#pragma unroll
        for (int j = 0; j < 4; j++) acc[i][j] = (v4f){0.f, 0.f, 0.f, 0.f};

    int r0 = row0 + l16;      if (r0 >= N_NODES) r0 = N_NODES - 1;
    int r1 = row0 + 16 + l16; if (r1 >= N_NODES) r1 = N_NODES - 1;
    const float4* a0p = (const float4*)(X + (size_t)r0 * 128) + quad * 2;
    const float4* a1p = (const float4*)(X + (size_t)r1 * 128) + quad * 2;
    const half8* bp[4];
#pragma unroll
    for (int ct = 0; ct < 4; ct++)
        bp[ct] = (const half8*)(Bt + (size_t)(colbase + ct * 16 + l16) * 128 + quad * 8);

#pragma unroll
    for (int kc = 0; kc < 4; kc++) {
        float4 f0 = a0p[kc * 8], f1 = a0p[kc * 8 + 1];
        float4 f2 = a1p[kc * 8], f3 = a1p[kc * 8 + 1];
        half8 av0 = (half8){(_Float16)f0.x, (_Float16)f0.y, (_Float16)f0.z, (_Float16)f0.w,
                            (_Float16)f1.x, (_Float16)f1.y, (_Float16)f1.z, (_Float16)f1.w};
        half8 av1 = (half8){(_Float16)f2.x, (_Float16)f2.y, (_Float16)f2.z, (_Float16)f2.w,
                            (_Float16)f3.x, (_Float16)f3.y, (_Float16)f3.z, (_Float16)f3.w};
#pragma unroll
        for (int ct = 0; ct < 4; ct++) {
            half8 bv = bp[ct][kc * 4];
            acc[0][ct] = __builtin_amdgcn_mfma_f32_16x16x32_f16(av0, bv, acc[0][ct], 0, 0, 0);
            acc[1][ct] = __builtin_amdgcn_mfma_f32_16x16x32_f16(av1, bv, acc[1][ct], 0, 0, 0);
        }
    }

    float asv[4], adv[4];
#pragma unroll
    for (int ct = 0; ct < 4; ct++) {
        asv[ct] = a_s[colbase + ct * 16 + l16];
        adv[ct] = a_d[colbase + ct * 16 + l16];
    }
#pragma unroll
    for (int rt = 0; rt < 2; rt++) {
#pragma unroll
        for (int hp = 0; hp < 2; hp++) {
#pragma unroll
            for (int reg = 0; reg < 4; reg++) {
                float ps = acc[rt][2 * hp][reg] * asv[2 * hp] +
                           acc[rt][2 * hp + 1][reg] * asv[2 * hp + 1];
                float pd = acc[rt][2 * hp][reg] * adv[2 * hp] +
                           acc[rt][2 * hp + 1][reg] * adv[2 * hp + 1];
#pragma unroll
                for (int mk = 1; mk < 16; mk <<= 1) {
                    ps += __shfl_xor(ps, mk, 64);
                    pd += __shfl_xor(pd, mk, 64);
                }
                if (l16 == 0) {
                    int row = row0 + rt * 16 + quad * 4 + reg;
                    if (row < N_NODES) {
                        int head = w * 2 + hp;
                        es[(size_t)row * 8 + head] = ps;
                        ed[(size_t)row * 8 + head] = pd;
                    }
                }
            }
        }
    }

    // 2-pass LDS-staged f16 store (16 rows per pass)
    __shared__ _Float16 SH[16][264];
#pragma unroll
    for (int rt = 0; rt < 2; rt++) {
        if (rt) __syncthreads();
#pragma unroll
        for (int ct = 0; ct < 4; ct++)
#pragma unroll
            for (int reg = 0; reg < 4; reg++)
                SH[quad * 4 + reg][colbase + ct * 16 + l16] = (_Float16)acc[rt][ct][reg];
        __syncthreads();
#pragma unroll
        for (int j = 0; j < 2; j++) {
            int c = j * 256 + t;
            int row = c >> 5, col8 = c & 31;
            int gr = row0 + rt * 16 + row;
            if (gr < N_NODES)
                *(half8*)(H + (size_t)gr * 256 + col8 * 8) = *(const half8*)&SH[row][col8 * 8];
        }
    }
}

// ------------------------------------------------------------------
// GEMM2: OUT[N,256] = A[N,256] @ w2t^T + bias, f32 out.
// 32-row tile; 2-pass LDS epilogue (16.6 KB).
// ------------------------------------------------------------------
__global__ __launch_bounds__(256) void k_gemm2(
    const _Float16* __restrict__ A, const _Float16* __restrict__ Bt,
    const float* __restrict__ bias, float* __restrict__ OUT) {
    int t = threadIdx.x, w = t >> 6, lane = t & 63;
    int quad = lane >> 4, l16 = lane & 15;
    int row0 = blockIdx.x * 32;
    int colbase = w * 64;

    v4f acc[2][4];
#pragma unroll
    for (int i = 0; i < 2; i++)
#pragma unroll
        for (int j = 0; j < 4; j++) acc[i][j] = (v4f){0.f, 0.f, 0.f, 0.f};

    int r0 = row0 + l16;      if (r0 >= N_NODES) r0 = N_NODES - 1;
    int r1 = row0 + 16 + l16; if (r1 >= N_NODES) r1 = N_NODES - 1;
    const half8* a0 = (const half8*)(A + (size_t)r0 * 256 + quad * 8);
    const half8* a1 = (const half8*)(A + (size_t)r1 * 256 + quad * 8);
    const half8* bp[4];
#pragma unroll
    for (int ct = 0; ct < 4; ct++)
        bp[ct] = (const half8*)(Bt + (size_t)(colbase + ct * 16 + l16) * 256 + quad * 8);

#pragma unroll
    for (int kc = 0; kc < 8; kc++) {
        half8 av0 = a0[kc * 4];
        half8 av1 = a1[kc * 4];
#pragma unroll
        for (int ct = 0; ct < 4; ct++) {
            half8 bv = bp[ct][kc * 4];
            acc[0][ct] = __builtin_amdgcn_mfma_f32_16x16x32_f16(av0, bv, acc[0][ct], 0, 0, 0);
            acc[1][ct] = __builtin_amdgcn_mfma_f32_16x16x32_f16(av1, bv, acc[1][ct], 0, 0, 0);
        }
    }

    __shared__ float SF[16][260];
#pragma unroll
    for (int rt = 0; rt < 2; rt++) {
        if (rt) __syncthreads();
#pragma unroll
        for (int ct = 0; ct < 4; ct++)
#pragma unroll
            for (int reg = 0; reg < 4; reg++)
                SF[quad * 4 + reg][colbase + ct * 16 + l16] = acc[rt][ct][reg];
        __syncthreads();
#pragma unroll
        for (int j = 0; j < 4; j++) {
            int c = j * 256 + t;
            int row = c >> 6, c4 = c & 63;
            int gr = row0 + rt * 16 + row;
            if (gr < N_NODES) {
                float4 v = *(const float4*)&SF[row][c4 * 4];
                float4 bb = ((const float4*)bias)[c4];
                float4 o = make_float4(v.x + bb.x, v.y + bb.y, v.z + bb.z, v.w + bb.w);
                *(float4*)(OUT + (size_t)gr * 256 + c4 * 4) = o;
            }
        }
    }
}

// ------------------------------------------------------------------
// Layer-1 aggregation (R7 structure, best measured): wave-per-node,
// inline weights, lane owns 4 channels, 4-edge unroll for MLP.
// Fused es2/ed2 epilogue.
// ------------------------------------------------------------------
__global__ __launch_bounds__(256) void k_agg1(
    const _Float16* __restrict__ H1, const float* __restrict__ es,
    const float* __restrict__ ed, const int* __restrict__ offsets,
    const int* __restrict__ csr_src, const float* __restrict__ b1,
    const float* __restrict__ vs2, const float* __restrict__ vd2,
    _Float16* __restrict__ out1, float* __restrict__ es2,
    float* __restrict__ ed2) {
    int t = threadIdx.x, w = t >> 6, lane = t & 63;
    int n = blockIdx.x * 4 + w;  // 12500 x 4 waves = 50000
    int hB = lane >> 3;          // head of this lane's 4 channels
    int beg = offsets[n];
    int deg = offsets[n + 1] - beg;
    float edl = ed[(size_t)n * 8 + hB];

    const char* __restrict__ Hb  = (const char*)H1 + lane * 8;
    const char* __restrict__ esb = (const char*)es + hB * 4;
    float a0 = 0.f, a1 = 0.f, a2 = 0.f, a3 = 0.f, den = 0.f;

    for (int base = 0; base < deg; base += 64) {
        int rem = deg - base; if (rem > 64) rem = 64;
        int idx = beg + base + lane;
        if (idx >= E_TOT) idx = E_TOT - 1;
        int sreg = csr_src[idx];
        int i = 0;
        for (; i + 3 < rem; i += 4) {
            int s0 = __shfl(sreg, i), s1 = __shfl(sreg, i + 1);
            int s2 = __shfl(sreg, i + 2), s3 = __shfl(sreg, i + 3);
            float l0 = *(const float*)(esb + ((unsigned)s0 << 5)) + edl;
            float l1 = *(const float*)(esb + ((unsigned)s1 << 5)) + edl;
            float l2 = *(const float*)(esb + ((unsigned)s2 << 5)) + edl;
            float l3 = *(const float*)(esb + ((unsigned)s3 << 5)) + edl;
            half4 h0 = *(const half4*)(Hb + ((unsigned)s0 << 9));
            half4 h1 = *(const half4*)(Hb + ((unsigned)s1 << 9));
            half4 h2 = *(const half4*)(Hb + ((unsigned)s2 << 9));
            half4 h3 = *(const half4*)(Hb + ((unsigned)s3 << 9));
            l0 = l0 > 0.f ? l0 : 0.2f * l0;
            l1 = l1 > 0.f ? l1 : 0.2f * l1;
            l2 = l2 > 0.f ? l2 : 0.2f * l2;
            l3 = l3 > 0.f ? l3 : 0.2f * l3;
            float w0 = __expf(l0), w1 = __expf(l1);
            float w2 = __expf(l2), w3 = __expf(l3);
            a0 += w0 * (float)h0[0]; a1 += w0 * (float)h0[1];
            a2 += w0 * (float)h0[2]; a3 += w0 * (float)h0[3];
            a0 += w1 * (float)h1[0]; a1 += w1 * (float)h1[1];
            a2 += w1 * (float)h1[2]; a3 += w1 * (float)h1[3];
            a0 += w2 * (float)h2[0]; a1 += w2 * (float)h2[1];
            a2 += w2 * (float)h2[2]; a3 += w2 * (float)h2[3];
            a0 += w3 * (float)h3[0]; a1 += w3 * (float)h3[1];
            a2 += w3 * (float)h3[2]; a3 += w3 * (float)h3[3];
            den += w0 + w1 + w2 + w3;
        }
        for (; i < rem; i++) {
            int s0 = __shfl(sreg, i);
            float l0 = *(const float*)(esb + ((unsigned)s0 << 5)) + edl;
            l0 = l0 > 0.f ? l0 : 0.2f * l0;
            float w0 = __expf(l0);
            half4 h0 = *(const half4*)(Hb + ((unsigned)s0 << 9));
            a0 += w0 * (float)h0[0]; a1 += w0 * (float)h0[1];
            a2 += w0 * (float)h0[2]; a3 += w0 * (float)h0[3];
            den += w0;
        }
    }

    float r = 1.f / (den + 1e-16f);
    float4 bb = ((const float4*)b1)[lane];
    float o0 = a0 * r + bb.x, o1 = a1 * r + bb.y;
    float o2 = a2 * r + bb.z, o3 = a3 * r + bb.w;
    o0 = o0 > 0.f ? o0 : __expf(o0) - 1.f;
    o1 = o1 > 0.f ? o1 : __expf(o1) - 1.f;
    o2 = o2 > 0.f ? o2 : __expf(o2) - 1.f;
    o3 = o3 > 0.f ? o3 : __expf(o3) - 1.f;
    ((half4*)(out1 + (size_t)n * 256))[lane] =
        (half4){(_Float16)o0, (_Float16)o1, (_Float16)o2, (_Float16)o3};

    // fused layer-2 attention coefficients
    float4 vs = ((const float4*)vs2)[lane];
    float4 vd = ((const float4*)vd2)[lane];
    float ps = o0 * vs.x + o1 * vs.y + o2 * vs.z + o3 * vs.w;
    float pd = o0 * vd.x + o1 * vd.y + o2 * vd.z + o3 * vd.w;
#pragma unroll
    for (int mk = 1; mk < 64; mk <<= 1) {
        ps += __shfl_xor(ps, mk, 64);
        pd += __shfl_xor(pd, mk, 64);
    }
    if (lane == 0) { es2[n] = ps; ed2[n] = pd; }
}

// ------------------------------------------------------------------
// Layer-2 aggregation (R7 structure): inline es2 weights, 4-edge
// unroll. Writes normalized aggregate f16 -> GEMM2 input.
// ------------------------------------------------------------------
__global__ __launch_bounds__(256) void k_agg2(
    const _Float16* __restrict__ O1, const float* __restrict__ es2,
    const float* __restrict__ ed2, const int* __restrict__ offsets,
    const int* __restrict__ csr_src, _Float16* __restrict__ xagg) {
    int t = threadIdx.x, w = t >> 6, lane = t & 63;
    int n = blockIdx.x * 4 + w;
    int beg = offsets[n];
    int deg = offsets[n + 1] - beg;
    float edn = ed2[n];

    const char* __restrict__ Ob  = (const char*)O1 + lane * 8;
    const char* __restrict__ eb  = (const char*)es2;
    float a0 = 0.f, a1 = 0.f, a2 = 0.f, a3 = 0.f, den = 0.f;

    for (int base = 0; base < deg; base += 64) {
        int rem = deg - base; if (rem > 64) rem = 64;
        int idx = beg + base + lane;
        if (idx >= E_TOT) idx = E_TOT - 1;
        int sreg = csr_src[idx];
        int i = 0;
        for (; i + 3 < rem; i += 4) {
            int s0 = __shfl(sreg, i), s1 = __shfl(sreg, i + 1);
            int s2 = __shfl(sreg, i + 2), s3 = __shfl(sreg, i + 3);
            float l0 = *(const float*)(eb + ((unsigned)s0 << 2)) + edn;
            float l1 = *(const float*)(eb + ((unsigned)s1 << 2)) + edn;
            float l2 = *(const float*)(eb + ((unsigned)s2 << 2)) + edn;
            float l3 = *(const float*)(eb + ((unsigned)s3 << 2)) + edn;
            half4 h0 = *(const half4*)(Ob + ((unsigned)s0 << 9));
            half4 h1 = *(const half4*)(Ob + ((unsigned)s1 << 9));
            half4 h2 = *(const half4*)(Ob + ((unsigned)s2 << 9));
            half4 h3 = *(const half4*)(Ob + ((unsigned)s3 << 9));
            l0 = l0 > 0.f ? l0 : 0.2f * l0;
            l1 = l1 > 0.f ? l1 : 0.2f * l1;
            l2 = l2 > 0.f ? l2 : 0.2f * l2;
            l3 = l3 > 0.f ? l3 : 0.2f * l3;
            float w0 = __expf(l0), w1 = __expf(l1);
            float w2 = __expf(l2), w3 = __expf(l3);
            a0 += w0 * (float)h0[0]; a1 += w0 * (float)h0[1];
            a2 += w0 * (float)h0[2]; a3 += w0 * (float)h0[3];
            a0 += w1 * (float)h1[0]; a1 += w1 * (float)h1[1];
            a2 += w1 * (float)h1[2]; a3 += w1 * (float)h1[3];
            a0 += w2 * (float)h2[0]; a1 += w2 * (float)h2[1];
            a2 += w2 * (float)h2[2]; a3 += w2 * (float)h2[3];
            a0 += w3 * (float)h3[0]; a1 += w3 * (float)h3[1];
            a2 += w3 * (float)h3[2]; a3 += w3 * (float)h3[3];
            den += w0 + w1 + w2 + w3;
        }
        for (; i < rem; i++) {
            int s0 = __shfl(sreg, i);
            float l0 = *(const float*)(eb + ((unsigned)s0 << 2)) + edn;
            l0 = l0 > 0.f ? l0 : 0.2f * l0;
            float w0 = __expf(l0);
            half4 h0 = *(const half4*)(Ob + ((unsigned)s0 << 9));
            a0 += w0 * (float)h0[0]; a1 += w0 * (float)h0[1];
            a2 += w0 * (float)h0[2]; a3 += w0 * (float)h0[3];
            den += w0;
        }
    }

    float r = 1.f / (den + 1e-16f);
    ((half4*)(xagg + (size_t)n * 256))[lane] =
        (half4){(_Float16)(a0 * r), (_Float16)(a1 * r),
                (_Float16)(a2 * r), (_Float16)(a3 * r)};
}

// ------------------------------------------------------------------
extern "C" void kernel_launch(void* const* d_in, const int* in_sizes, int n_in,
                              void* d_out, int out_size, void* d_ws, size_t ws_size,
                              hipStream_t stream) {
    const float* x   = (const float*)d_in[0];
    const int*   ei  = (const int*)d_in[1];
    const float* W1  = (const float*)d_in[2];
    const float* as1 = (const float*)d_in[3];
    const float* ad1 = (const float*)d_in[4];
    const float* b1  = (const float*)d_in[5];
    const float* W2  = (const float*)d_in[6];
    const float* as2 = (const float*)d_in[7];
    const float* ad2 = (const float*)d_in[8];
    const float* b2  = (const float*)d_in[9];
    float* out = (float*)d_out;

    char* ws = (char*)d_ws;
    size_t off = 0;
    auto alloc = [&](size_t bytes) {
        void* p = ws + off;
        off = (off + bytes + 255) & ~(size_t)255;
        return p;
    };
    _Float16* h1h     = (_Float16*)alloc((size_t)N_NODES * 256 * 2);
    _Float16* out1h   = (_Float16*)alloc((size_t)N_NODES * 256 * 2);
    _Float16* xagg    = (_Float16*)alloc((size_t)N_NODES * 256 * 2);
    _Float16* w1t     = (_Float16*)alloc((size_t)128 * 256 * 2);
    _Float16* w2t     = (_Float16*)alloc((size_t)256 * 256 * 2);
    float*    es1     = (float*)alloc((size_t)N_NODES * 8 * 4);
    float*    ed1     = (float*)alloc((size_t)N_NODES * 8 * 4);
    float*    es2     = (float*)alloc((size_t)N_NODES * 4);
    float*    ed2     = (float*)alloc((size_t)N_NODES * 4);
    float*    vs2     = (float*)alloc(256 * 4);
    float*    vd2     = (float*)alloc(256 * 4);
    int*      deg     = (int*)alloc((size_t)N_NODES * 4);
    int*      offsets = (int*)alloc((size_t)(N_NODES + 1) * 4);
    int*      cur     = (int*)alloc((size_t)N_NODES * 4);
    int*      csr_src = (int*)alloc((size_t)E_TOT * 4);
    int*      bsum    = (int*)alloc((size_t)NB * 4);
    int*      boff    = (int*)alloc((size_t)(NB + 1) * 4);

    const int TB = 256;
    int gridE = (E_TOT + TB - 1) / TB;
    int gridG = (N_NODES + 31) / 32;   // 32-row GEMM tiles
    int gridA = N_NODES / 4;           // wave-per-node

    // CSR build (deg zeroed by memset; count fused into prepw)
    hipMemsetAsync(deg, 0, (size_t)N_NODES * 4, stream);
    int prepN = E_TOT + 128 * 256 + 256 * 256 + 256;
    k_prepw<<<(prepN + TB - 1) / TB, TB, 0, stream>>>(W1, W2, as2, ad2, ei,
                                                      w1t, w2t, vs2, vd2, deg);
    k_blocksum<<<NB, TB, 0, stream>>>(deg, bsum);
    k_scanbsum<<<1, TB, 0, stream>>>(bsum, boff);
    k_offsets<<<NB, TB, 0, stream>>>(deg, boff, offsets, cur);
    k_scatter<<<gridE, TB, 0, stream>>>(ei, cur, csr_src);

    // layer 1
    k_gemm1<<<gridG, TB, 0, stream>>>(x, w1t, as1, ad1, h1h, es1, ed1);
    k_agg1<<<gridA, TB, 0, stream>>>(h1h, es1, ed1, offsets, csr_src, b1,
                                     vs2, vd2, out1h, es2, ed2);

    // layer 2: aggregate first (linearity), then GEMM straight to d_out
    k_agg2<<<gridA, TB, 0, stream>>>(out1h, es2, ed2, offsets, csr_src, xagg);
    k_gemm2<<<gridG, TB, 0, stream>>>(xagg, w2t, b2, out);
}